// Round 6
// baseline (253.827 us; speedup 1.0000x reference)
//
#include <hip/hip_runtime.h>
#include <math.h>

constexpr int K = 512;
constexpr int D = 64;
constexpr int HW = 64 * 64;                      // 4096
constexpr int NPIX = 131072;
constexpr long long NELEM = (long long)NPIX * D; // 8388608
constexpr float BETA = 0.25f;
constexpr int PPB = 128;                         // pixels per block (vq)
constexpr int NBLK = NPIX / PPB;                 // 1024 blocks
constexpr int ZBLK = 1024;                       // zq_write blocks (8192 out-elems each)

typedef __attribute__((ext_vector_type(8))) short short8;
typedef __attribute__((ext_vector_type(16))) float f32x16;

__device__ inline unsigned short bf16rne(float x) {
    unsigned u = __float_as_uint(x);
    unsigned r = (u + 0x7FFFu + ((u >> 16) & 1u)) >> 16;
    return (unsigned short)r;
}

__device__ inline void async_cp16(const void* g, void* l) {
    __builtin_amdgcn_global_load_lds(
        (const __attribute__((address_space(1))) void*)g,
        (__attribute__((address_space(3))) void*)l, 16, 0, 0);
}

__device__ inline int padi(int s) { return s + (s >> 5); }  // LDS bank swizzle

// E[n][k] -> bf16 hi/lo of -2E in MFMA-B frag order + exact fp32 ee[n].
// Also zeroes counts / sse / ticket.
__global__ __launch_bounds__(256) void prep_kernel(
    const float* __restrict__ E, float* __restrict__ ee,
    unsigned short* __restrict__ ebhi, unsigned short* __restrict__ eblo,
    unsigned int* __restrict__ counts, float* __restrict__ sse,
    unsigned int* __restrict__ ticket) {
    int gid = blockIdx.x * 256 + threadIdx.x;   // 0..32767
    if (gid < K) counts[gid] = 0u;
    if (gid == K) { *sse = 0.f; *ticket = 0u; }
    int n = gid >> 6, k = gid & 63;
    float v = E[gid];
    float a = v * v;
#pragma unroll
    for (int off = 32; off > 0; off >>= 1) a += __shfl_down(a, off, 64);
    if ((threadIdx.x & 63) == 0) ee[n] = a;
    float m2 = -2.f * v;
    unsigned short hi = bf16rne(m2);
    unsigned short lo = bf16rne(m2 - __uint_as_float((unsigned)hi << 16));
    int idx = ((n >> 5) * 4 + (k >> 4)) * 512 + ((k >> 3) & 1) * 256 + (n & 31) * 8 + (k & 7);
    ebhi[idx] = hi;
    eblo[idx] = lo;
}

// Pass 1: argmin per pixel -> bks_g (short), histogram -> counts, SSE -> sse_acc.
// NO writes to out (keeps the write path clean for zq_write).
__global__ __launch_bounds__(256, 4) void vq_mfma(
    const float* __restrict__ z, const float* __restrict__ ee,
    const unsigned short* __restrict__ ebhi, const unsigned short* __restrict__ eblo,
    unsigned short* __restrict__ bks_g, float* __restrict__ sse_acc,
    unsigned int* __restrict__ counts) {

    __shared__ __align__(16) unsigned short sbh[8192];  // 16 KB: 128-code chunk (hi)
    __shared__ __align__(16) unsigned short sbl[8192];  // 16 KB: (lo)
    __shared__ int bks[PPB];
    __shared__ unsigned int hcnt[K];

    const int tid = threadIdx.x;
    const int wave = tid >> 6;
    const int lane = tid & 63;
    const int ln = lane & 31;
    const int half = lane >> 5;
    const int wb = wave * 64;

    const int p0 = blockIdx.x * PPB;
    const int b = p0 >> 12;
    const int s0 = p0 & (HW - 1);
    const int wpix = s0 + wave * 32;            // this wave's 32 pixels

    hcnt[tid] = 0u; hcnt[tid + 256] = 0u;

    // issue async copy of B-chunk 0 (codes 0..127) while we load A
#pragma unroll
    for (int r = 0; r < 4; ++r) {
        async_cp16(ebhi + (r * 256 + tid) * 8, &sbh[(r * 256 + wb) * 8]);
        async_cp16(eblo + (r * 256 + tid) * 8, &sbl[(r * 256 + wb) * 8]);
    }

    // Load A (z) for this wave's 32-row tile, split to bf16 hi/lo.
    // A-frag 32x32x16: m = lane&31, k = ks*16 + (lane>>5)*8 + j
    const float* zb = z + (size_t)b * (D * HW) + wpix;
    short8 ahi[4], alo[4];
    float zsq = 0.f;
#pragma unroll
    for (int ks = 0; ks < 4; ++ks) {
#pragma unroll
        for (int j = 0; j < 8; ++j) {
            float v = zb[(size_t)(ks * 16 + half * 8 + j) * HW + ln];
            zsq = fmaf(v, v, zsq);
            unsigned short h = bf16rne(v);
            unsigned short l = bf16rne(v - __uint_as_float((unsigned)h << 16));
            ahi[ks][j] = (short)h;
            alo[ks][j] = (short)l;
        }
    }

    float best[16];
#pragma unroll
    for (int r = 0; r < 16; ++r) best[r] = __uint_as_float(0x7F800000u);

    // Main loop: 4 chunks x 4 tiles; single-buffered LDS
    for (int c = 0; c < 4; ++c) {
        __syncthreads();   // chunk-c copy complete
#pragma unroll
        for (int tt = 0; tt < 4; ++tt) {
            float et = ee[(c * 4 + tt) * 32 + ln];
            short8 vbh[4], vbl[4];
#pragma unroll
            for (int ks = 0; ks < 4; ++ks) {
                vbh[ks] = *(const short8*)&sbh[tt * 2048 + ks * 512 + lane * 8];
                vbl[ks] = *(const short8*)&sbl[tt * 2048 + ks * 512 + lane * 8];
            }
            f32x16 acc = {0,0,0,0,0,0,0,0,0,0,0,0,0,0,0,0};
#pragma unroll
            for (int ks = 0; ks < 4; ++ks) {
                acc = __builtin_amdgcn_mfma_f32_32x32x16_bf16(ahi[ks], vbh[ks], acc, 0, 0, 0);
                acc = __builtin_amdgcn_mfma_f32_32x32x16_bf16(alo[ks], vbh[ks], acc, 0, 0, 0);
                acc = __builtin_amdgcn_mfma_f32_32x32x16_bf16(ahi[ks], vbl[ks], acc, 0, 0, 0);
            }
            unsigned cb = (unsigned)((c * 4 + tt) * 32 + ln);
#pragma unroll
            for (int r = 0; r < 16; ++r) {
                float d = acc[r] + et;
                float kk = __uint_as_float((__float_as_uint(d) & 0xFFFFFE00u) | cb);
                best[r] = fminf(best[r], kk);
            }
        }
        __syncthreads();   // all waves done reading chunk c
        if (c < 3) {
#pragma unroll
            for (int r = 0; r < 4; ++r) {
                async_cp16(ebhi + (c + 1) * 8192 + (r * 256 + tid) * 8, &sbh[(r * 256 + wb) * 8]);
                async_cp16(eblo + (c + 1) * 8192 + (r * 256 + tid) * 8, &sbl[(r * 256 + wb) * 8]);
            }
        }
    }

    // Cross-lane argmin (butterfly over 32 cols).  SSE = sum||z||^2 + sum bestd.
    float lsse = zsq;
#pragma unroll
    for (int r = 0; r < 16; ++r) {
        float v = best[r];
#pragma unroll
        for (int m = 1; m < 32; m <<= 1) v = fminf(v, __shfl_xor(v, m, 64));
        if (ln == r) {
            int row = (r & 3) + 8 * (r >> 2) + 4 * half;
            unsigned u = __float_as_uint(v);
            int cw = (int)(u & 0x1FFu);
            bks[wave * 32 + row] = cw;
            atomicAdd(&hcnt[cw], 1u);
            lsse += __uint_as_float(u & 0xFFFFFE00u);
        }
    }
#pragma unroll
    for (int off = 32; off > 0; off >>= 1) lsse += __shfl_down(lsse, off, 64);
    if (lane == 0) atomicAdd(sse_acc, lsse);

    __syncthreads();

    // write bks (coalesced shorts) + flush histogram
    if (tid < PPB) bks_g[p0 + tid] = (unsigned short)bks[tid];
    unsigned hc0 = hcnt[tid], hc1 = hcnt[tid + 256];
    if (hc0) atomicAdd(&counts[tid], hc0);
    if (hc1) atomicAdd(&counts[tid + 256], hc1);
}

// Pass 2: each block writes one contiguous 32 KB span of out (2 d-planes of one
// image) with aligned float4 stores -- every 128B line written once, by one block.
__global__ __launch_bounds__(256, 4) void zq_write(
    const float* __restrict__ E, const unsigned short* __restrict__ bks_g,
    float* __restrict__ out, int out_size, const unsigned int* __restrict__ counts,
    const float* __restrict__ sse, unsigned int* __restrict__ ticket) {

    __shared__ int bkl[4096 + 128];     // padded: index padi(s)
    __shared__ float tab[2][512];       // codebook columns d0, d1
    __shared__ float red[4];
    __shared__ int sflag;

    const int t = blockIdx.x;
    const int tid = threadIdx.x;
    const int b = t >> 5;               // image
    const int d0 = (t & 31) * 2;        // this block's two d-planes

    // load this image's bks (4096 shorts = 8 KB) into padded LDS ints
    const uint4* bi4 = (const uint4*)(bks_g + b * 4096);   // 512 x 16B
#pragma unroll
    for (int r = 0; r < 2; ++r) {
        uint4 v = bi4[r * 256 + tid];
        int base = (r * 256 + tid) * 8;
        unsigned w[4] = {v.x, v.y, v.z, v.w};
#pragma unroll
        for (int q = 0; q < 4; ++q) {
            bkl[padi(base + 2 * q)] = (int)(w[q] & 0xFFFFu);
            bkl[padi(base + 2 * q + 1)] = (int)(w[q] >> 16);
        }
    }
    // load codebook columns d0, d0+1 (float2 per code)
#pragma unroll
    for (int r = 0; r < 2; ++r) {
        int k = r * 256 + tid;
        float2 v = *(const float2*)(E + k * D + d0);
        tab[0][k] = v.x;
        tab[1][k] = v.y;
    }
    __syncthreads();

    // out element e = t*8192 + tid*32 + j  ->  value for g = e-1
    const size_t ebase = (size_t)t * 8192 + (size_t)tid * 32;
    float vals[32];
#pragma unroll
    for (int j = 0; j < 32; ++j) {
        int gl = tid * 32 + j - 1;                 // local g in [-1, 8191)
        int s = gl & 4095;
        int dsel = (gl >> 12) & 1;
        float v = (dsel == 0) ? tab[0][bkl[padi(s)]] : tab[1][bkl[padi(s)]];
        vals[j] = v;
    }
    if (tid == 0 && t > 0) {
        // stray first element: g = t*8192 - 1 (previous pair / previous image)
        long long gg = (long long)t * 8192 - 1;
        int bs = (int)(gg >> 18);
        int ds = (int)((gg >> 12) & 63);
        vals[0] = E[(int)bks_g[bs * 4096 + 4095] * D + ds];
    }

    float* op = out + ebase;
    if (t == 0 && tid == 0) {
        // skip e=0 (loss slot)
        op[1] = vals[1]; op[2] = vals[2]; op[3] = vals[3];
#pragma unroll
        for (int q = 1; q < 8; ++q)
            *(float4*)(op + 4 * q) = make_float4(vals[4 * q], vals[4 * q + 1], vals[4 * q + 2], vals[4 * q + 3]);
    } else {
#pragma unroll
        for (int q = 0; q < 8; ++q)
            *(float4*)(op + 4 * q) = make_float4(vals[4 * q], vals[4 * q + 1], vals[4 * q + 2], vals[4 * q + 3]);
    }
    if (t == ZBLK - 1 && tid == 255) {
        // final z_q element e = 8388608 (g = 8388607: s=4095, dsel=1)
        out[(size_t)ZBLK * 8192] = tab[1][bkl[padi(4095)]];
    }

    // fused finalize: last block computes loss + perplexity
    __syncthreads();
    if (tid == 0) {
        __threadfence();
        unsigned tk = atomicAdd(ticket, 1u);
        sflag = (tk == (unsigned)(ZBLK - 1)) ? 1 : 0;
    }
    __syncthreads();
    if (sflag) {
        float c0f = (float)counts[tid];
        float c1f = (float)counts[tid + 256];
        float pa = c0f / (float)NPIX + 1e-10f;
        float pb = c1f / (float)NPIX + 1e-10f;
        float tt = pa * logf(pa) + pb * logf(pb);
#pragma unroll
        for (int off = 32; off > 0; off >>= 1) tt += __shfl_down(tt, off, 64);
        if ((tid & 63) == 0) red[tid >> 6] = tt;
        __syncthreads();
        if (tid == 0) {
            float tot = red[0] + red[1] + red[2] + red[3];
            out[0] = (1.f + BETA) * sse[0] / (float)NELEM;
            out[out_size - 1] = expf(-tot);
        }
    }
}

extern "C" void kernel_launch(void* const* d_in, const int* in_sizes, int n_in,
                              void* d_out, int out_size, void* d_ws, size_t ws_size,
                              hipStream_t stream) {
    const float* z = (const float*)d_in[0];
    const float* E = (const float*)d_in[1];
    float* out = (float*)d_out;

    float* wsf = (float*)d_ws;
    float* sse = wsf;                                           // [0]
    unsigned int* ticket = (unsigned int*)(wsf + 1);            // [1]
    unsigned int* counts = (unsigned int*)(wsf + 4);            // 512 uints
    float* ee = wsf + 4 + K;                                    // 512 floats
    unsigned short* ebhi = (unsigned short*)(wsf + 4 + 2 * K);  // 32768 ushort (16B aligned)
    unsigned short* eblo = ebhi + K * D;                        // 32768 ushort
    unsigned short* bks_g = eblo + K * D;                       // 131072 ushort (256 KB)

    prep_kernel<<<128, 256, 0, stream>>>(E, ee, ebhi, eblo, counts, sse, ticket);
    vq_mfma<<<NBLK, 256, 0, stream>>>(z, ee, ebhi, eblo, bks_g, sse, counts);
    zq_write<<<ZBLK, 256, 0, stream>>>(E, bks_g, out, out_size, counts, sse, ticket);
}

// Round 7
// 167.566 us; speedup vs baseline: 1.5148x; 1.5148x over previous
//
#include <hip/hip_runtime.h>
#include <math.h>

constexpr int K = 512;
constexpr int D = 64;
constexpr int HW = 64 * 64;                      // 4096
constexpr int NPIX = 131072;
constexpr long long NELEM = (long long)NPIX * D; // 8388608
constexpr float BETA = 0.25f;
constexpr int PPB = 256;                         // pixels per block
constexpr int NBLK = NPIX / PPB;                 // 512 blocks

typedef __attribute__((ext_vector_type(8))) short short8;
typedef __attribute__((ext_vector_type(16))) float f32x16;

__device__ inline unsigned short bf16rne(float x) {
    unsigned u = __float_as_uint(x);
    unsigned r = (u + 0x7FFFu + ((u >> 16) & 1u)) >> 16;
    return (unsigned short)r;
}

__device__ inline void async_cp16(const void* g, void* l) {
    __builtin_amdgcn_global_load_lds(
        (const __attribute__((address_space(1))) void*)g,
        (__attribute__((address_space(3))) void*)l, 16, 0, 0);
}

// E[n][k] -> bf16 hi/lo of -2E in MFMA-B frag order + exact fp32 ee[n].
// Also zeroes counts / sse / ticket.
__global__ __launch_bounds__(256) void prep_kernel(
    const float* __restrict__ E, float* __restrict__ ee,
    unsigned short* __restrict__ ebhi, unsigned short* __restrict__ eblo,
    unsigned int* __restrict__ counts, float* __restrict__ sse,
    unsigned int* __restrict__ ticket) {
    int gid = blockIdx.x * 256 + threadIdx.x;   // 0..32767
    if (gid < K) counts[gid] = 0u;
    if (gid == K) { *sse = 0.f; *ticket = 0u; }
    int n = gid >> 6, k = gid & 63;
    float v = E[gid];
    float a = v * v;
#pragma unroll
    for (int off = 32; off > 0; off >>= 1) a += __shfl_down(a, off, 64);
    if ((threadIdx.x & 63) == 0) ee[n] = a;
    float m2 = -2.f * v;
    unsigned short hi = bf16rne(m2);
    unsigned short lo = bf16rne(m2 - __uint_as_float((unsigned)hi << 16));
    int idx = ((n >> 5) * 4 + (k >> 4)) * 512 + ((k >> 3) & 1) * 256 + (n & 31) * 8 + (k & 7);
    ebhi[idx] = hi;
    eblo[idx] = lo;
}

// Fused: barrier-free MFMA argmin loop (full B resident in LDS) + z_q write +
// histogram + SSE + ticket-finalize.
__global__ __launch_bounds__(256, 2) void vq_fused(
    const float* __restrict__ z, const float* __restrict__ E,
    const float* __restrict__ ee, const unsigned short* __restrict__ ebhi,
    const unsigned short* __restrict__ eblo, float* __restrict__ out,
    int out_size, float* __restrict__ sse_acc,
    unsigned int* __restrict__ counts, unsigned int* __restrict__ ticket) {

    __shared__ __align__(16) unsigned short sbh[32768];  // 64 KB? no: 32768 ushort = 64 KB hi
    __shared__ __align__(16) unsigned short sbl[32768];  // this is 64 KB... (see note below)
    // NOTE: 32768 ushorts = 64 KB each would be 128 KB total -> too big for 2 blocks/CU.
    // B hi = K*D ushort = 32768 ushort = 64 KB. So hi+lo = 128 KB; at 2 blocks/CU = 256 KB > 160 KB.
    // => stage hi fully (64 KB) and lo in the SAME buffer? No. Instead: hi+lo interleaved
    // per-chunk is required. Solution: use ONE buffer of 96 KB? Simplest correct fit:
    // keep hi fully resident (64 KB) + lo streamed in 2 halves (16 KB x2) with 2 barriers.
    __shared__ int bks[PPB];
    __shared__ unsigned int hcnt[K];
    __shared__ float red[4];
    __shared__ int sflag;

    const int tid = threadIdx.x;
    const int wave = tid >> 6;
    const int lane = tid & 63;
    const int ln = lane & 31;
    const int half = lane >> 5;
    const int wb = wave * 64;

    const int p0 = blockIdx.x * PPB;
    const int b = p0 >> 12;
    const int s0 = p0 & (HW - 1);
    const int wpix = s0 + wave * 64;            // this wave's 64 pixels (2 row-tiles)

    hcnt[tid] = 0u; hcnt[tid + 256] = 0u;

    // ---- stage ALL of B-hi (64 KB) and B-lo (64 KB) via async copies ----
    // sbh holds hi for all 16 col-tiles; sbl likewise for lo.
#pragma unroll
    for (int i = 0; i < 16; ++i) {
        async_cp16(ebhi + (i * 256 + tid) * 8, &sbh[(i * 256 + wb) * 8]);
        async_cp16(eblo + (i * 256 + tid) * 8, &sbl[(i * 256 + wb) * 8]);
    }

    // ---- Load A (z) for 2 row-tiles, split to bf16 hi/lo ----
    // A-frag 32x32x16: m = lane&31, k = ks*16 + (lane>>5)*8 + j
    const float* zb = z + (size_t)b * (D * HW) + wpix;
    short8 ahi0[4], alo0[4], ahi1[4], alo1[4];
    float zsq = 0.f;
#pragma unroll
    for (int ks = 0; ks < 4; ++ks) {
#pragma unroll
        for (int j = 0; j < 8; ++j) {
            size_t doff = (size_t)(ks * 16 + half * 8 + j) * HW;
            float v0 = zb[doff + ln];
            float v1 = zb[doff + 32 + ln];
            zsq = fmaf(v0, v0, zsq);
            zsq = fmaf(v1, v1, zsq);
            unsigned short h0 = bf16rne(v0);
            unsigned short l0 = bf16rne(v0 - __uint_as_float((unsigned)h0 << 16));
            unsigned short h1 = bf16rne(v1);
            unsigned short l1 = bf16rne(v1 - __uint_as_float((unsigned)h1 << 16));
            ahi0[ks][j] = (short)h0; alo0[ks][j] = (short)l0;
            ahi1[ks][j] = (short)h1; alo1[ks][j] = (short)l1;
        }
    }

    // preload ee into registers (16 values per lane)
    float eet[16];
#pragma unroll
    for (int t = 0; t < 16; ++t) eet[t] = ee[t * 32 + ln];

    float best0[16], best1[16];
#pragma unroll
    for (int r = 0; r < 16; ++r) {
        best0[r] = __uint_as_float(0x7F800000u);
        best1[r] = __uint_as_float(0x7F800000u);
    }

    __syncthreads();   // B fully resident; barrier-free from here

    // ---- Main loop: 16 col-tiles, no barriers ----
#pragma unroll 1
    for (int t = 0; t < 16; ++t) {
        short8 vbh[4], vbl[4];
#pragma unroll
        for (int ks = 0; ks < 4; ++ks) {
            vbh[ks] = *(const short8*)&sbh[t * 2048 + ks * 512 + lane * 8];
            vbl[ks] = *(const short8*)&sbl[t * 2048 + ks * 512 + lane * 8];
        }
        f32x16 acc0 = {0,0,0,0,0,0,0,0,0,0,0,0,0,0,0,0};
        f32x16 acc1 = {0,0,0,0,0,0,0,0,0,0,0,0,0,0,0,0};
#pragma unroll
        for (int ks = 0; ks < 4; ++ks) {
            acc0 = __builtin_amdgcn_mfma_f32_32x32x16_bf16(ahi0[ks], vbh[ks], acc0, 0, 0, 0);
            acc1 = __builtin_amdgcn_mfma_f32_32x32x16_bf16(ahi1[ks], vbh[ks], acc1, 0, 0, 0);
            acc0 = __builtin_amdgcn_mfma_f32_32x32x16_bf16(alo0[ks], vbh[ks], acc0, 0, 0, 0);
            acc1 = __builtin_amdgcn_mfma_f32_32x32x16_bf16(alo1[ks], vbh[ks], acc1, 0, 0, 0);
            acc0 = __builtin_amdgcn_mfma_f32_32x32x16_bf16(ahi0[ks], vbl[ks], acc0, 0, 0, 0);
            acc1 = __builtin_amdgcn_mfma_f32_32x32x16_bf16(ahi1[ks], vbl[ks], acc1, 0, 0, 0);
        }
        float et = eet[t];
        unsigned cb = (unsigned)(t * 32 + ln);
#pragma unroll
        for (int r = 0; r < 16; ++r) {
            float d0 = acc0[r] + et;
            float d1 = acc1[r] + et;
            best0[r] = fminf(best0[r], __uint_as_float((__float_as_uint(d0) & 0xFFFFFE00u) | cb));
            best1[r] = fminf(best1[r], __uint_as_float((__float_as_uint(d1) & 0xFFFFFE00u) | cb));
        }
    }

    // ---- Cross-lane argmin (butterfly over 32 cols) + SSE ----
    float lsse = zsq;
#pragma unroll
    for (int r = 0; r < 16; ++r) {
        float v0 = best0[r], v1 = best1[r];
#pragma unroll
        for (int m = 1; m < 32; m <<= 1) {
            v0 = fminf(v0, __shfl_xor(v0, m, 64));
            v1 = fminf(v1, __shfl_xor(v1, m, 64));
        }
        if (ln == r) {
            int row = (r & 3) + 8 * (r >> 2) + 4 * half;
            unsigned u0 = __float_as_uint(v0), u1 = __float_as_uint(v1);
            int c0 = (int)(u0 & 0x1FFu), c1 = (int)(u1 & 0x1FFu);
            bks[wave * 64 + row] = c0;
            bks[wave * 64 + 32 + row] = c1;
            atomicAdd(&hcnt[c0], 1u);
            atomicAdd(&hcnt[c1], 1u);
            lsse += __uint_as_float(u0 & 0xFFFFFE00u) + __uint_as_float(u1 & 0xFFFFFE00u);
        }
    }
#pragma unroll
    for (int off = 32; off > 0; off >>= 1) lsse += __shfl_down(lsse, off, 64);
    if (lane == 0) atomicAdd(sse_acc, lsse);

    __syncthreads();

    // ---- Epilogue: thread = one pixel; gather E row (L2-hot), write z_q ----
    int bk = bks[tid];
    const float4* Er = (const float4*)(E + bk * D);
    float* ob = out + 1 + (size_t)b * (D * HW) + s0 + tid;
#pragma unroll
    for (int q = 0; q < 16; ++q) {
        float4 e4 = Er[q];
        ob[(size_t)(4 * q + 0) * HW] = e4.x;
        ob[(size_t)(4 * q + 1) * HW] = e4.y;
        ob[(size_t)(4 * q + 2) * HW] = e4.z;
        ob[(size_t)(4 * q + 3) * HW] = e4.w;
    }

    // ---- flush histogram ----
    unsigned hc0 = hcnt[tid], hc1 = hcnt[tid + 256];
    if (hc0) atomicAdd(&counts[tid], hc0);
    if (hc1) atomicAdd(&counts[tid + 256], hc1);

    // ---- fused finalize: last block computes loss + perplexity ----
    __syncthreads();
    if (tid == 0) {
        __threadfence();
        unsigned t = atomicAdd(ticket, 1u);
        sflag = (t == (unsigned)(NBLK - 1)) ? 1 : 0;
    }
    __syncthreads();
    if (sflag) {
        float c0f = (float)counts[tid];
        float c1f = (float)counts[tid + 256];
        float pa = c0f / (float)NPIX + 1e-10f;
        float pb = c1f / (float)NPIX + 1e-10f;
        float t = pa * logf(pa) + pb * logf(pb);
#pragma unroll
        for (int off = 32; off > 0; off >>= 1) t += __shfl_down(t, off, 64);
        if (lane == 0) red[wave] = t;
        __syncthreads();
        if (tid == 0) {
            float tot = red[0] + red[1] + red[2] + red[3];
            float s = sse_acc[0];
            out[0] = (1.f + BETA) * s / (float)NELEM;
            out[out_size - 1] = expf(-tot);
        }
    }
}

extern "C" void kernel_launch(void* const* d_in, const int* in_sizes, int n_in,
                              void* d_out, int out_size, void* d_ws, size_t ws_size,
                              hipStream_t stream) {
    const float* z = (const float*)d_in[0];
    const float* E = (const float*)d_in[1];
    float* out = (float*)d_out;

    float* wsf = (float*)d_ws;
    float* sse = wsf;                                           // [0]
    unsigned int* ticket = (unsigned int*)(wsf + 1);            // [1]
    unsigned int* counts = (unsigned int*)(wsf + 4);            // 512 uints
    float* ee = wsf + 4 + K;                                    // 512 floats
    unsigned short* ebhi = (unsigned short*)(wsf + 4 + 2 * K);  // 32768 ushort (16B aligned)
    unsigned short* eblo = ebhi + K * D;                        // 32768 ushort

    prep_kernel<<<128, 256, 0, stream>>>(E, ee, ebhi, eblo, counts, sse, ticket);
    vq_fused<<<NBLK, 256, 0, stream>>>(z, E, ee, ebhi, eblo, out, out_size, sse, counts, ticket);
}

// Round 8
// 148.179 us; speedup vs baseline: 1.7130x; 1.1308x over previous
//
#include <hip/hip_runtime.h>
#include <math.h>

constexpr int K = 512;
constexpr int D = 64;
constexpr int HW = 64 * 64;                      // 4096
constexpr int NPIX = 131072;
constexpr long long NELEM = (long long)NPIX * D; // 8388608
constexpr float BETA = 0.25f;
constexpr int PPB = 512;                         // pixels per block
constexpr int NBLK = NPIX / PPB;                 // 256 blocks == CU count

typedef __attribute__((ext_vector_type(8))) short short8;
typedef __attribute__((ext_vector_type(16))) float f32x16;

__device__ inline unsigned short bf16rne(float x) {
    unsigned u = __float_as_uint(x);
    unsigned r = (u + 0x7FFFu + ((u >> 16) & 1u)) >> 16;
    return (unsigned short)r;
}

// zero counts / sse / ticket (ws is poisoned 0xAA before every launch)
__global__ __launch_bounds__(512) void init_kernel(
    unsigned int* __restrict__ counts, float* __restrict__ sse,
    unsigned int* __restrict__ ticket) {
    counts[threadIdx.x] = 0u;
    if (threadIdx.x == 0) { *sse = 0.f; *ticket = 0u; }
}

// ONE kernel: per-block B-fragment build (E -> bf16 hi/lo -2E frags in LDS) +
// barrier-free MFMA argmin + z_q write + histogram + SSE + ticket finalize.
__global__ __launch_bounds__(512, 2) void vq_one(
    const float* __restrict__ z, const float* __restrict__ E,
    float* __restrict__ out, int out_size, float* __restrict__ sse_acc,
    unsigned int* __restrict__ counts, unsigned int* __restrict__ ticket) {

    __shared__ __align__(16) unsigned short sbh[32768];  // 64 KB: B hi frags (16 tiles x 4 KB)
    __shared__ __align__(16) unsigned short sbl[32768];  // 64 KB: B lo frags
    __shared__ float see[K];                             // ||e_k||^2
    __shared__ int bks[PPB];
    __shared__ unsigned int hcnt[K];
    __shared__ float red[8];
    __shared__ int sflag;

    const int tid = threadIdx.x;
    const int wave = tid >> 6;      // 0..7
    const int lane = tid & 63;
    const int ln = lane & 31;
    const int half = lane >> 5;

    const int p0 = blockIdx.x * PPB;
    const int b = p0 >> 12;
    const int s0 = p0 & (HW - 1);
    const int wpix = s0 + wave * 64;            // this wave's 64 pixels (2 row-tiles)

    hcnt[tid] = 0u;

    // ---- Build B fragments in LDS: thread tid converts codebook row n = tid ----
    // frag layout (ushort idx): tile(n>>5)*2048 + ks*512 + khalf*256 + (n&31)*8 + j
    {
        const int n = tid;
        const float4* er = (const float4*)(E + n * D);
        float4 v4[16];
#pragma unroll
        for (int q = 0; q < 16; ++q) v4[q] = er[q];
        float acc = 0.f;
        const int boff = (n >> 5) * 2048 + (n & 31) * 8;   // ushort offset
#pragma unroll
        for (int ks = 0; ks < 4; ++ks) {
#pragma unroll
            for (int h = 0; h < 2; ++h) {
                short8 sh, sl;
#pragma unroll
                for (int j = 0; j < 8; ++j) {
                    int k = ks * 16 + h * 8 + j;
                    const float* vp = (const float*)&v4[k >> 2];
                    float v = vp[k & 3];
                    acc = fmaf(v, v, acc);
                    float m2 = -2.f * v;
                    unsigned short hi = bf16rne(m2);
                    unsigned short lo = bf16rne(m2 - __uint_as_float((unsigned)hi << 16));
                    sh[j] = (short)hi;
                    sl[j] = (short)lo;
                }
                int off = boff + ks * 512 + h * 256;
                *(short8*)&sbh[off] = sh;
                *(short8*)&sbl[off] = sl;
            }
        }
        see[n] = acc;
    }

    // ---- Load A (z) for 2 row-tiles, split to bf16 hi/lo ----
    // A-frag 32x32x16: m = lane&31, k = ks*16 + (lane>>5)*8 + j
    const float* zb = z + (size_t)b * (D * HW) + wpix;
    short8 ahi0[4], alo0[4], ahi1[4], alo1[4];
    float zsq = 0.f;
#pragma unroll
    for (int ks = 0; ks < 4; ++ks) {
#pragma unroll
        for (int j = 0; j < 8; ++j) {
            size_t doff = (size_t)(ks * 16 + half * 8 + j) * HW;
            float v0 = zb[doff + ln];
            float v1 = zb[doff + 32 + ln];
            zsq = fmaf(v0, v0, zsq);
            zsq = fmaf(v1, v1, zsq);
            unsigned short h0 = bf16rne(v0);
            unsigned short l0 = bf16rne(v0 - __uint_as_float((unsigned)h0 << 16));
            unsigned short h1 = bf16rne(v1);
            unsigned short l1 = bf16rne(v1 - __uint_as_float((unsigned)h1 << 16));
            ahi0[ks][j] = (short)h0; alo0[ks][j] = (short)l0;
            ahi1[ks][j] = (short)h1; alo1[ks][j] = (short)l1;
        }
    }

    float best0[16], best1[16];
#pragma unroll
    for (int r = 0; r < 16; ++r) {
        best0[r] = __uint_as_float(0x7F800000u);
        best1[r] = __uint_as_float(0x7F800000u);
    }

    __syncthreads();   // B frags + see resident; barrier-free from here

    float eet[16];
#pragma unroll
    for (int t = 0; t < 16; ++t) eet[t] = see[t * 32 + ln];

    // ---- Main loop: 16 col-tiles, no barriers ----
#pragma unroll 1
    for (int t = 0; t < 16; ++t) {
        short8 vbh[4], vbl[4];
#pragma unroll
        for (int ks = 0; ks < 4; ++ks) {
            vbh[ks] = *(const short8*)&sbh[t * 2048 + ks * 512 + lane * 8];
            vbl[ks] = *(const short8*)&sbl[t * 2048 + ks * 512 + lane * 8];
        }
        f32x16 acc0 = {0,0,0,0,0,0,0,0,0,0,0,0,0,0,0,0};
        f32x16 acc1 = {0,0,0,0,0,0,0,0,0,0,0,0,0,0,0,0};
#pragma unroll
        for (int ks = 0; ks < 4; ++ks) {
            acc0 = __builtin_amdgcn_mfma_f32_32x32x16_bf16(ahi0[ks], vbh[ks], acc0, 0, 0, 0);
            acc1 = __builtin_amdgcn_mfma_f32_32x32x16_bf16(ahi1[ks], vbh[ks], acc1, 0, 0, 0);
            acc0 = __builtin_amdgcn_mfma_f32_32x32x16_bf16(alo0[ks], vbh[ks], acc0, 0, 0, 0);
            acc1 = __builtin_amdgcn_mfma_f32_32x32x16_bf16(alo1[ks], vbh[ks], acc1, 0, 0, 0);
            acc0 = __builtin_amdgcn_mfma_f32_32x32x16_bf16(ahi0[ks], vbl[ks], acc0, 0, 0, 0);
            acc1 = __builtin_amdgcn_mfma_f32_32x32x16_bf16(ahi1[ks], vbl[ks], acc1, 0, 0, 0);
        }
        float et = eet[t];
        unsigned cb = (unsigned)(t * 32 + ln);
#pragma unroll
        for (int r = 0; r < 16; ++r) {
            float d0 = acc0[r] + et;
            float d1 = acc1[r] + et;
            best0[r] = fminf(best0[r], __uint_as_float((__float_as_uint(d0) & 0xFFFFFE00u) | cb));
            best1[r] = fminf(best1[r], __uint_as_float((__float_as_uint(d1) & 0xFFFFFE00u) | cb));
        }
    }

    // ---- Cross-lane argmin (butterfly over 32 cols) + SSE ----
    // SSE = sum ||z||^2 + sum bestd (bestd = -2 z.e + ||e||^2, low bits masked)
    float lsse = zsq;
#pragma unroll
    for (int r = 0; r < 16; ++r) {
        float v0 = best0[r], v1 = best1[r];
#pragma unroll
        for (int m = 1; m < 32; m <<= 1) {
            v0 = fminf(v0, __shfl_xor(v0, m, 64));
            v1 = fminf(v1, __shfl_xor(v1, m, 64));
        }
        if (ln == r) {
            int row = (r & 3) + 8 * (r >> 2) + 4 * half;
            unsigned u0 = __float_as_uint(v0), u1 = __float_as_uint(v1);
            int c0 = (int)(u0 & 0x1FFu), c1 = (int)(u1 & 0x1FFu);
            bks[wave * 64 + row] = c0;
            bks[wave * 64 + 32 + row] = c1;
            atomicAdd(&hcnt[c0], 1u);
            atomicAdd(&hcnt[c1], 1u);
            lsse += __uint_as_float(u0 & 0xFFFFFE00u) + __uint_as_float(u1 & 0xFFFFFE00u);
        }
    }
#pragma unroll
    for (int off = 32; off > 0; off >>= 1) lsse += __shfl_down(lsse, off, 64);
    if (lane == 0) atomicAdd(sse_acc, lsse);

    __syncthreads();

    // ---- Epilogue: thread = one pixel; gather E row (L2-hot), write z_q ----
    int bk = bks[tid];
    const float4* Er = (const float4*)(E + bk * D);
    float* ob = out + 1 + (size_t)b * (D * HW) + s0 + tid;
#pragma unroll
    for (int q = 0; q < 16; ++q) {
        float4 e4 = Er[q];
        ob[(size_t)(4 * q + 0) * HW] = e4.x;
        ob[(size_t)(4 * q + 1) * HW] = e4.y;
        ob[(size_t)(4 * q + 2) * HW] = e4.z;
        ob[(size_t)(4 * q + 3) * HW] = e4.w;
    }

    // ---- flush histogram ----
    unsigned hc = hcnt[tid];
    if (hc) atomicAdd(&counts[tid], hc);

    // ---- fused finalize: last block computes loss + perplexity ----
    __syncthreads();
    if (tid == 0) {
        __threadfence();
        unsigned t = atomicAdd(ticket, 1u);
        sflag = (t == (unsigned)(NBLK - 1)) ? 1 : 0;
    }
    __syncthreads();
    if (sflag) {
        float cf = (float)atomicAdd(&counts[tid], 0u);
        float pa = cf / (float)NPIX + 1e-10f;
        float t = pa * logf(pa);
#pragma unroll
        for (int off = 32; off > 0; off >>= 1) t += __shfl_down(t, off, 64);
        if (lane == 0) red[wave] = t;
        __syncthreads();
        if (tid == 0) {
            float tot = 0.f;
#pragma unroll
            for (int i = 0; i < 8; ++i) tot += red[i];
            float s = atomicAdd(sse_acc, 0.0f);
            out[0] = (1.f + BETA) * s / (float)NELEM;
            out[out_size - 1] = expf(-tot);
        }
    }
}

extern "C" void kernel_launch(void* const* d_in, const int* in_sizes, int n_in,
                              void* d_out, int out_size, void* d_ws, size_t ws_size,
                              hipStream_t stream) {
    const float* z = (const float*)d_in[0];
    const float* E = (const float*)d_in[1];
    float* out = (float*)d_out;

    float* wsf = (float*)d_ws;
    float* sse = wsf;                                  // [0]
    unsigned int* ticket = (unsigned int*)(wsf + 1);   // [1]
    unsigned int* counts = (unsigned int*)(wsf + 4);   // 512 uints

    init_kernel<<<1, 512, 0, stream>>>(counts, sse, ticket);
    vq_one<<<NBLK, 512, 0, stream>>>(z, E, out, out_size, sse, counts, ticket);
}

// Round 9
// 129.671 us; speedup vs baseline: 1.9575x; 1.1427x over previous
//
#include <hip/hip_runtime.h>
#include <math.h>

constexpr int K = 512;
constexpr int D = 64;
constexpr int HW = 64 * 64;                      // 4096
constexpr int NPIX = 131072;
constexpr long long NELEM = (long long)NPIX * D; // 8388608
constexpr float BETA = 0.25f;
constexpr int PPB = 256;                         // pixels per block
constexpr int NBLK = NPIX / PPB;                 // 512 blocks (2 per CU)

typedef __attribute__((ext_vector_type(8))) short short8;
typedef __attribute__((ext_vector_type(16))) float f32x16;

__device__ inline unsigned short bf16rne(float x) {
    unsigned u = __float_as_uint(x);
    unsigned r = (u + 0x7FFFu + ((u >> 16) & 1u)) >> 16;
    return (unsigned short)r;
}

__global__ __launch_bounds__(512) void init_kernel(
    unsigned int* __restrict__ counts, unsigned int* __restrict__ ticket) {
    counts[threadIdx.x] = 0u;
    if (threadIdx.x == 0) *ticket = 0u;
}

// Single fused kernel. bf16 single-term distances; ||e||^2 folded into the MFMA
// via a k-extension (A=(1,1), B=(ee_hi,ee_lo)); packed-key argmin; z_q gather;
// histogram; SSE; ticket finalize.
__global__ __launch_bounds__(256, 2) void vq_one(
    const float* __restrict__ z, const float* __restrict__ E,
    float* __restrict__ out, int out_size, float* __restrict__ sse_arr,
    unsigned int* __restrict__ counts, unsigned int* __restrict__ ticket) {

    __shared__ __align__(16) unsigned short sbh[32768];  // 64 KB: bf16(-2E) B-frags
    __shared__ unsigned int eepk[K];                     // 2 KB: (ee_hi | ee_lo<<16)
    __shared__ int bks[PPB];                             // 1 KB
    __shared__ unsigned int hcnt[K];                     // 2 KB
    __shared__ float red[4];
    __shared__ int sflag;

    const int tid = threadIdx.x;
    const int wave = tid >> 6;      // 0..3
    const int lane = tid & 63;
    const int ln = lane & 31;
    const int half = lane >> 5;

    const int p0 = blockIdx.x * PPB;
    const int b = p0 >> 12;
    const int s0 = p0 & (HW - 1);
    const int wpix = s0 + wave * 64;            // this wave's 64 pixels (2 row-tiles)

    hcnt[tid] = 0u; hcnt[tid + 256] = 0u;

    // ---- Build B fragments + ee table: thread handles codebook rows tid, tid+256 ----
    // frag idx: (n>>5)*2048 + ks*512 + h*256 + (n&31)*8 + j   for k = ks*16+h*8+j
#pragma unroll
    for (int rr = 0; rr < 2; ++rr) {
        const int n = rr * 256 + tid;
        const float4* er = (const float4*)(E + n * D);
        float4 v4[16];
#pragma unroll
        for (int q = 0; q < 16; ++q) v4[q] = er[q];
        float acc = 0.f;
        const int boff = (n >> 5) * 2048 + (n & 31) * 8;
#pragma unroll
        for (int ks = 0; ks < 4; ++ks) {
#pragma unroll
            for (int h = 0; h < 2; ++h) {
                short8 sh;
#pragma unroll
                for (int j = 0; j < 8; ++j) {
                    int k = ks * 16 + h * 8 + j;
                    const float* vp = (const float*)&v4[k >> 2];
                    float v = vp[k & 3];
                    acc = fmaf(v, v, acc);
                    sh[j] = (short)bf16rne(-2.f * v);
                }
                *(short8*)&sbh[boff + ks * 512 + h * 256] = sh;
            }
        }
        unsigned short eh = bf16rne(acc);
        unsigned short el = bf16rne(acc - __uint_as_float((unsigned)eh << 16));
        eepk[n] = (unsigned)eh | ((unsigned)el << 16);
    }

    // ---- Load A (z) for 2 row-tiles, single bf16; exact fp32 ||z||^2 partial ----
    // A-frag 32x32x16: m = lane&31, k = ks*16 + (lane>>5)*8 + j
    const float* zb = z + (size_t)b * (D * HW) + wpix;
    short8 a0[4], a1[4];
    float zsq = 0.f;
#pragma unroll
    for (int ks = 0; ks < 4; ++ks) {
#pragma unroll
        for (int j = 0; j < 8; ++j) {
            size_t doff = (size_t)(ks * 16 + half * 8 + j) * HW;
            float v0 = zb[doff + ln];
            float v1 = zb[doff + 32 + ln];
            zsq = fmaf(v0, v0, zsq);
            zsq = fmaf(v1, v1, zsq);
            a0[ks][j] = (short)bf16rne(v0);
            a1[ks][j] = (short)bf16rne(v1);
        }
    }

    // A-operand for the ee fold-in: rows all get k0=k1=1.0 (half 0, j=0,1)
    short8 aee = {0, 0, 0, 0, 0, 0, 0, 0};
    if (half == 0) { aee[0] = (short)0x3F80; aee[1] = (short)0x3F80; }

    float best0[16], best1[16];
#pragma unroll
    for (int r = 0; r < 16; ++r) {
        best0[r] = __uint_as_float(0x7F800000u);
        best1[r] = __uint_as_float(0x7F800000u);
    }

    __syncthreads();   // B frags + eepk resident; barrier-free main loop

    // ---- Main loop: 16 col-tiles ----
#pragma unroll 1
    for (int t = 0; t < 16; ++t) {
        short8 vb[4];
#pragma unroll
        for (int ks = 0; ks < 4; ++ks)
            vb[ks] = *(const short8*)&sbh[t * 2048 + ks * 512 + lane * 8];
        unsigned ep = eepk[t * 32 + ln];
        short8 bee = {0, 0, 0, 0, 0, 0, 0, 0};
        if (half == 0) { bee[0] = (short)(ep & 0xFFFFu); bee[1] = (short)(ep >> 16); }

        f32x16 acc0 = {0,0,0,0,0,0,0,0,0,0,0,0,0,0,0,0};
        f32x16 acc1 = {0,0,0,0,0,0,0,0,0,0,0,0,0,0,0,0};
#pragma unroll
        for (int ks = 0; ks < 4; ++ks) {
            acc0 = __builtin_amdgcn_mfma_f32_32x32x16_bf16(a0[ks], vb[ks], acc0, 0, 0, 0);
            acc1 = __builtin_amdgcn_mfma_f32_32x32x16_bf16(a1[ks], vb[ks], acc1, 0, 0, 0);
        }
        acc0 = __builtin_amdgcn_mfma_f32_32x32x16_bf16(aee, bee, acc0, 0, 0, 0);
        acc1 = __builtin_amdgcn_mfma_f32_32x32x16_bf16(aee, bee, acc1, 0, 0, 0);

        unsigned cb = (unsigned)(t * 32 + ln);
#pragma unroll
        for (int r = 0; r < 16; ++r) {
            best0[r] = fminf(best0[r], __uint_as_float((__float_as_uint(acc0[r]) & 0xFFFFFE00u) | cb));
            best1[r] = fminf(best1[r], __uint_as_float((__float_as_uint(acc1[r]) & 0xFFFFFE00u) | cb));
        }
    }

    // ---- Cross-lane argmin + SSE (SSE = sum||z||^2 + sum masked bestd) ----
    float lsse = zsq;
#pragma unroll
    for (int r = 0; r < 16; ++r) {
        float v0 = best0[r], v1 = best1[r];
#pragma unroll
        for (int m = 1; m < 32; m <<= 1) {
            v0 = fminf(v0, __shfl_xor(v0, m, 64));
            v1 = fminf(v1, __shfl_xor(v1, m, 64));
        }
        if (ln == r) {
            int row = (r & 3) + 8 * (r >> 2) + 4 * half;
            unsigned u0 = __float_as_uint(v0), u1 = __float_as_uint(v1);
            int c0 = (int)(u0 & 0x1FFu), c1 = (int)(u1 & 0x1FFu);
            bks[wave * 64 + row] = c0;
            bks[wave * 64 + 32 + row] = c1;
            atomicAdd(&hcnt[c0], 1u);
            atomicAdd(&hcnt[c1], 1u);
            lsse += __uint_as_float(u0 & 0xFFFFFE00u) + __uint_as_float(u1 & 0xFFFFFE00u);
        }
    }
#pragma unroll
    for (int off = 32; off > 0; off >>= 1) lsse += __shfl_down(lsse, off, 64);
    if (lane == 0) red[wave] = lsse;

    __syncthreads();
    if (tid == 0) sse_arr[blockIdx.x] = red[0] + red[1] + red[2] + red[3];

    // ---- Epilogue: thread = one pixel; gather E row (L2-hot), write z_q ----
    int bk = bks[tid];
    const float4* Er = (const float4*)(E + bk * D);
    float* ob = out + 1 + (size_t)b * (D * HW) + s0 + tid;
#pragma unroll
    for (int q = 0; q < 16; ++q) {
        float4 e4 = Er[q];
        ob[(size_t)(4 * q + 0) * HW] = e4.x;
        ob[(size_t)(4 * q + 1) * HW] = e4.y;
        ob[(size_t)(4 * q + 2) * HW] = e4.z;
        ob[(size_t)(4 * q + 3) * HW] = e4.w;
    }

    // ---- flush histogram ----
    unsigned hc0 = hcnt[tid], hc1 = hcnt[tid + 256];
    if (hc0) atomicAdd(&counts[tid], hc0);
    if (hc1) atomicAdd(&counts[tid + 256], hc1);

    // ---- fused finalize: last block computes loss + perplexity ----
    __syncthreads();
    if (tid == 0) {
        __threadfence();
        unsigned t = atomicAdd(ticket, 1u);
        sflag = (t == (unsigned)(NBLK - 1)) ? 1 : 0;
    }
    __syncthreads();
    if (sflag) {
        float c0f = (float)atomicAdd(&counts[tid], 0u);
        float c1f = (float)atomicAdd(&counts[tid + 256], 0u);
        float pa = c0f / (float)NPIX + 1e-10f;
        float pb = c1f / (float)NPIX + 1e-10f;
        float t = pa * logf(pa) + pb * logf(pb);
        float s = atomicAdd(&sse_arr[tid], 0.0f) + atomicAdd(&sse_arr[tid + 256], 0.0f);
#pragma unroll
        for (int off = 32; off > 0; off >>= 1) {
            t += __shfl_down(t, off, 64);
            s += __shfl_down(s, off, 64);
        }
        if (lane == 0) { red[wave] = t; ((float*)bks)[wave] = s; }
        __syncthreads();
        if (tid == 0) {
            float tot = red[0] + red[1] + red[2] + red[3];
            float st = ((float*)bks)[0] + ((float*)bks)[1] + ((float*)bks)[2] + ((float*)bks)[3];
            out[0] = (1.f + BETA) * st / (float)NELEM;
            out[out_size - 1] = expf(-tot);
        }
    }
}

extern "C" void kernel_launch(void* const* d_in, const int* in_sizes, int n_in,
                              void* d_out, int out_size, void* d_ws, size_t ws_size,
                              hipStream_t stream) {
    const float* z = (const float*)d_in[0];
    const float* E = (const float*)d_in[1];
    float* out = (float*)d_out;

    float* wsf = (float*)d_ws;
    unsigned int* ticket = (unsigned int*)wsf;         // [0]
    unsigned int* counts = (unsigned int*)(wsf + 4);   // 512 uints
    float* sse_arr = wsf + 4 + K;                      // 512 floats (written unconditionally)

    init_kernel<<<1, 512, 0, stream>>>(counts, ticket);
    vq_one<<<NBLK, 256, 0, stream>>>(z, E, out, out_size, sse_arr, counts, ticket);
}

// Round 10
// 129.605 us; speedup vs baseline: 1.9585x; 1.0005x over previous
//
#include <hip/hip_runtime.h>
#include <math.h>

constexpr int K = 512;
constexpr int D = 64;
constexpr int HW = 64 * 64;                      // 4096
constexpr int NPIX = 131072;
constexpr long long NELEM = (long long)NPIX * D; // 8388608
constexpr float BETA = 0.25f;
constexpr int PPB = 256;                         // pixels per block
constexpr int NBLK = NPIX / PPB;                 // 512 blocks (2 per CU)

typedef __attribute__((ext_vector_type(8))) short short8;
typedef __attribute__((ext_vector_type(16))) float f32x16;

union frag_u { uint4 u; short8 s; };

__device__ inline unsigned short bf16rne(float x) {
    unsigned u = __float_as_uint(x);
    unsigned r = (u + 0x7FFFu + ((u >> 16) & 1u)) >> 16;
    return (unsigned short)r;
}

// pack truncated-bf16(f0) into low ushort, truncated-bf16(f1) into high ushort
// one v_perm_b32: D.b0=f0.b2 D.b1=f0.b3 D.b2=f1.b2 D.b3=f1.b3
__device__ inline unsigned pk(float f0, float f1) {
    return __builtin_amdgcn_perm(__float_as_uint(f1), __float_as_uint(f0), 0x07060302u);
}

// Single fused kernel: per-block B build (perm-packed bf16 of -2E in LDS) +
// barrier-free MFMA argmin (ee folded via k-extension) + z_q + hist + SSE +
// ticket finalize.  512 thr / 256 px / 512 blocks = 2 blocks/CU, 16 waves/CU.
__global__ __launch_bounds__(512, 4) void vq_one(
    const float* __restrict__ z, const float* __restrict__ E,
    float* __restrict__ out, int out_size, float* __restrict__ sse_arr,
    unsigned int* __restrict__ counts, unsigned int* __restrict__ ticket) {

    __shared__ __align__(16) unsigned short sbh[32768];  // 64 KB: bf16(-2E) B-frags
    __shared__ unsigned int eepk[K];                     // 2 KB: ee hi|lo packed
    __shared__ int bks[PPB];                             // 1 KB
    __shared__ unsigned int hcnt[K];                     // 2 KB
    __shared__ float red[8], red2[8];
    __shared__ int sflag;

    const int tid = threadIdx.x;
    const int wave = tid >> 6;      // 0..7
    const int lane = tid & 63;
    const int ln = lane & 31;
    const int half = lane >> 5;

    const int p0 = blockIdx.x * PPB;
    const int b = p0 >> 12;
    const int s0 = p0 & (HW - 1);

    hcnt[tid] = 0u;

    // ---- A loads first (latency hidden under B build) ----
    // wave owns 32 px (one row-tile): m = ln, k = ks*16 + half*8 + j
    const float* zb = z + (size_t)b * (D * HW) + s0 + wave * 32;
    float av[4][8];
#pragma unroll
    for (int ks = 0; ks < 4; ++ks)
#pragma unroll
        for (int j = 0; j < 8; ++j)
            av[ks][j] = zb[(size_t)(ks * 16 + half * 8 + j) * HW + ln];

    // ---- Build B fragments + ee: thread = codebook row n = tid ----
    {
        const int n = tid;
        const float4* er = (const float4*)(E + n * D);
        float4 v4[16];
#pragma unroll
        for (int q = 0; q < 16; ++q) v4[q] = er[q];
        float acc = 0.f;
        const float* vp = (const float*)v4;
#pragma unroll
        for (int k = 0; k < 64; ++k) acc = fmaf(vp[k], vp[k], acc);
        const int boff = (n >> 5) * 2048 + (n & 31) * 8;
#pragma unroll
        for (int ks = 0; ks < 4; ++ks) {
#pragma unroll
            for (int h = 0; h < 2; ++h) {
                const float* e8 = vp + ks * 16 + h * 8;
                uint4 w;
                w.x = pk(-2.f * e8[0], -2.f * e8[1]);
                w.y = pk(-2.f * e8[2], -2.f * e8[3]);
                w.z = pk(-2.f * e8[4], -2.f * e8[5]);
                w.w = pk(-2.f * e8[6], -2.f * e8[7]);
                *(uint4*)&sbh[boff + ks * 512 + h * 256] = w;
            }
        }
        unsigned short eh = bf16rne(acc);
        unsigned short el = bf16rne(acc - __uint_as_float((unsigned)eh << 16));
        eepk[n] = (unsigned)eh | ((unsigned)el << 16);
    }

    // ---- Convert A: perm-pack + exact fp32 ||z||^2 partial ----
    frag_u a[4];
    float zsq = 0.f;
#pragma unroll
    for (int ks = 0; ks < 4; ++ks) {
#pragma unroll
        for (int j = 0; j < 8; ++j) zsq = fmaf(av[ks][j], av[ks][j], zsq);
        a[ks].u.x = pk(av[ks][0], av[ks][1]);
        a[ks].u.y = pk(av[ks][2], av[ks][3]);
        a[ks].u.z = pk(av[ks][4], av[ks][5]);
        a[ks].u.w = pk(av[ks][6], av[ks][7]);
    }

    // ee fold-in A operand: k slots 0,1 = 1.0 (half 0 only)
    short8 aee = {0, 0, 0, 0, 0, 0, 0, 0};
    if (half == 0) { aee[0] = (short)0x3F80; aee[1] = (short)0x3F80; }

    float best[16];
#pragma unroll
    for (int r = 0; r < 16; ++r) best[r] = __uint_as_float(0x7F800000u);

    __syncthreads();   // B + eepk resident; barrier-free main loop

    // ---- Main loop: 8 x 2 col-tiles ----
#pragma unroll 1
    for (int t2 = 0; t2 < 8; ++t2) {
        const int ta = 2 * t2, tb = 2 * t2 + 1;
        frag_u vba[4], vbb[4];
#pragma unroll
        for (int ks = 0; ks < 4; ++ks) {
            vba[ks].u = *(const uint4*)&sbh[ta * 2048 + ks * 512 + lane * 8];
            vbb[ks].u = *(const uint4*)&sbh[tb * 2048 + ks * 512 + lane * 8];
        }
        unsigned epa = eepk[ta * 32 + ln], epb = eepk[tb * 32 + ln];
        short8 beea = {0,0,0,0,0,0,0,0}, beeb = {0,0,0,0,0,0,0,0};
        if (half == 0) {
            beea[0] = (short)(epa & 0xFFFFu); beea[1] = (short)(epa >> 16);
            beeb[0] = (short)(epb & 0xFFFFu); beeb[1] = (short)(epb >> 16);
        }

        f32x16 acca = {0,0,0,0,0,0,0,0,0,0,0,0,0,0,0,0};
        f32x16 accb = {0,0,0,0,0,0,0,0,0,0,0,0,0,0,0,0};
#pragma unroll
        for (int ks = 0; ks < 4; ++ks) {
            acca = __builtin_amdgcn_mfma_f32_32x32x16_bf16(a[ks].s, vba[ks].s, acca, 0, 0, 0);
            accb = __builtin_amdgcn_mfma_f32_32x32x16_bf16(a[ks].s, vbb[ks].s, accb, 0, 0, 0);
        }
        acca = __builtin_amdgcn_mfma_f32_32x32x16_bf16(aee, beea, acca, 0, 0, 0);
        accb = __builtin_amdgcn_mfma_f32_32x32x16_bf16(aee, beeb, accb, 0, 0, 0);

        unsigned cba = (unsigned)(ta * 32 + ln), cbb = (unsigned)(tb * 32 + ln);
#pragma unroll
        for (int r = 0; r < 16; ++r) {
            float ka = __uint_as_float((__float_as_uint(acca[r]) & 0xFFFFFE00u) | cba);
            float kb = __uint_as_float((__float_as_uint(accb[r]) & 0xFFFFFE00u) | cbb);
            best[r] = fminf(fminf(best[r], ka), kb);   // v_min3_f32
        }
    }

    // ---- Cross-lane argmin + SSE (SSE = sum||z||^2 + sum masked bestd) ----
    float lsse = zsq;
#pragma unroll
    for (int r = 0; r < 16; ++r) {
        float v = best[r];
#pragma unroll
        for (int m = 1; m < 32; m <<= 1) v = fminf(v, __shfl_xor(v, m, 64));
        if (ln == r) {
            int row = (r & 3) + 8 * (r >> 2) + 4 * half;   // row in 32-row tile
            unsigned u = __float_as_uint(v);
            int c = (int)(u & 0x1FFu);
            bks[wave * 32 + row] = c;
            atomicAdd(&hcnt[c], 1u);
            lsse += __uint_as_float(u & 0xFFFFFE00u);
        }
    }
#pragma unroll
    for (int off = 32; off > 0; off >>= 1) lsse += __shfl_down(lsse, off, 64);
    if (lane == 0) red[wave] = lsse;

    __syncthreads();
    if (tid == 0) {
        float s = 0.f;
#pragma unroll
        for (int i = 0; i < 8; ++i) s += red[i];
        sse_arr[blockIdx.x] = s;
    }

    // ---- Epilogue: thread -> (pixel = tid&255, d-half = tid>>8) ----
    {
        int q = tid & (PPB - 1);
        int dh = tid >> 8;
        int bk = bks[q];
        const float4* Er = (const float4*)(E + bk * D + dh * 32);
        float* ob = out + 1 + (size_t)b * (D * HW) + (size_t)dh * 32 * HW + s0 + q;
#pragma unroll
        for (int v4i = 0; v4i < 8; ++v4i) {
            float4 e4 = Er[v4i];
            ob[(size_t)(4 * v4i + 0) * HW] = e4.x;
            ob[(size_t)(4 * v4i + 1) * HW] = e4.y;
            ob[(size_t)(4 * v4i + 2) * HW] = e4.z;
            ob[(size_t)(4 * v4i + 3) * HW] = e4.w;
        }
    }

    // ---- flush histogram ----
    unsigned hc = hcnt[tid];
    if (hc) atomicAdd(&counts[tid], hc);

    // ---- fused finalize: last block computes loss + perplexity ----
    __syncthreads();
    if (tid == 0) {
        __threadfence();
        unsigned t = atomicAdd(ticket, 1u);
        sflag = (t == (unsigned)(NBLK - 1)) ? 1 : 0;
    }
    __syncthreads();
    if (sflag) {
        float cf = (float)atomicAdd(&counts[tid], 0u);
        float pa = cf / (float)NPIX + 1e-10f;
        float t = pa * logf(pa);
        float s = atomicAdd(&sse_arr[tid], 0.0f);   // 512 blocks -> 512 slots
#pragma unroll
        for (int off = 32; off > 0; off >>= 1) {
            t += __shfl_down(t, off, 64);
            s += __shfl_down(s, off, 64);
        }
        if (lane == 0) { red[wave] = t; red2[wave] = s; }
        __syncthreads();
        if (tid == 0) {
            float tot = 0.f, st = 0.f;
#pragma unroll
            for (int i = 0; i < 8; ++i) { tot += red[i]; st += red2[i]; }
            out[0] = (1.f + BETA) * st / (float)NELEM;
            out[out_size - 1] = expf(-tot);
        }
    }
}

extern "C" void kernel_launch(void* const* d_in, const int* in_sizes, int n_in,
                              void* d_out, int out_size, void* d_ws, size_t ws_size,
                              hipStream_t stream) {
    const float* z = (const float*)d_in[0];
    const float* E = (const float*)d_in[1];
    float* out = (float*)d_out;

    float* wsf = (float*)d_ws;
    unsigned int* ticket = (unsigned int*)wsf;         // [0] (+pad)
    unsigned int* counts = (unsigned int*)(wsf + 4);   // 512 uints
    float* sse_arr = wsf + 4 + K;                      // 512 floats (written unconditionally)

    hipMemsetAsync(d_ws, 0, (4 + K) * sizeof(float), stream);   // ticket + counts
    vq_one<<<NBLK, 512, 0, stream>>>(z, E, out, out_size, sse_arr, counts, ticket);
}

// Round 11
// 128.068 us; speedup vs baseline: 1.9820x; 1.0120x over previous
//
#include <hip/hip_runtime.h>
#include <math.h>

constexpr int K = 512;
constexpr int D = 64;
constexpr int HW = 64 * 64;                      // 4096
constexpr int NPIX = 131072;
constexpr long long NELEM = (long long)NPIX * D; // 8388608
constexpr float BETA = 0.25f;
constexpr int PPB = 256;                         // pixels per block
constexpr int NBLK = NPIX / PPB;                 // 512 blocks (2 per CU)

typedef __attribute__((ext_vector_type(8))) short short8;
typedef __attribute__((ext_vector_type(4))) float f32x4;

union frag_u { uint4 u; short8 s; };

__device__ inline unsigned short bf16rne(float x) {
    unsigned u = __float_as_uint(x);
    unsigned r = (u + 0x7FFFu + ((u >> 16) & 1u)) >> 16;
    return (unsigned short)r;
}

// truncated-bf16 pack: f0 -> low ushort, f1 -> high ushort (one v_perm_b32)
__device__ inline unsigned pk(float f0, float f1) {
    return __builtin_amdgcn_perm(__float_as_uint(f1), __float_as_uint(f0), 0x07060302u);
}

// Single fused kernel, 16x16x32 MFMA (4-reg accs -> all-VGPR, no AGPR traffic).
// Wave = 2 row-tiles x 16 px = 32 px; block = 512 thr = 256 px; 512 blocks.
__global__ __launch_bounds__(512, 4) void vq_one(
    const float* __restrict__ z, const float* __restrict__ E,
    float* __restrict__ out, int out_size, float* __restrict__ sse_arr,
    unsigned int* __restrict__ counts, unsigned int* __restrict__ ticket) {

    __shared__ __align__(16) unsigned short sb[32768];   // 64 KB: B-frags, slot (tile*2+c)*512+lane*8
    __shared__ unsigned int eepk[K];                     // ee hi|lo packed bf16
    __shared__ int bks[PPB];
    __shared__ unsigned int hcnt[K];
    __shared__ float red[8], red2[8];
    __shared__ int sflag;

    const int tid = threadIdx.x;
    const int wave = tid >> 6;      // 0..7
    const int lane = tid & 63;
    const int quad = lane >> 4;     // k-group
    const int lx = lane & 15;       // m (row) for A, n (col) for B, col for C/D

    const int p0 = blockIdx.x * PPB;
    const int b = p0 >> 12;
    const int s0 = p0 & (HW - 1);

    hcnt[tid] = 0u;

    // ---- A loads: av[rt][c][j] = z[px = wave*32+rt*16+lx][k = c*32+quad*8+j] ----
    const float* zb = z + (size_t)b * (D * HW) + s0 + wave * 32;
    float av[2][2][8];
#pragma unroll
    for (int rt = 0; rt < 2; ++rt)
#pragma unroll
        for (int c = 0; c < 2; ++c)
#pragma unroll
            for (int j = 0; j < 8; ++j)
                av[rt][c][j] = zb[(size_t)(c * 32 + quad * 8 + j) * HW + rt * 16 + lx];

    // ---- B build: thread = codebook row n; frag B[k=quad*8+j][n=lx] ----
    {
        const int n = tid;
        const float4* er = (const float4*)(E + n * D);
        float4 v4[16];
#pragma unroll
        for (int q = 0; q < 16; ++q) v4[q] = er[q];
        const float* vp = (const float*)v4;
        float acc = 0.f;
#pragma unroll
        for (int k = 0; k < 64; ++k) acc = fmaf(vp[k], vp[k], acc);
        const int tile = n >> 4;
        const int col = n & 15;
#pragma unroll
        for (int c = 0; c < 2; ++c) {
#pragma unroll
            for (int g = 0; g < 4; ++g) {
                const float* e8 = vp + c * 32 + g * 8;
                uint4 w;
                w.x = pk(-2.f * e8[0], -2.f * e8[1]);
                w.y = pk(-2.f * e8[2], -2.f * e8[3]);
                w.z = pk(-2.f * e8[4], -2.f * e8[5]);
                w.w = pk(-2.f * e8[6], -2.f * e8[7]);
                *(uint4*)&sb[((tile * 2 + c) * 512) + (g * 16 + col) * 8] = w;
            }
        }
        unsigned short eh = bf16rne(acc);
        unsigned short el = bf16rne(acc - __uint_as_float((unsigned)eh << 16));
        eepk[n] = (unsigned)eh | ((unsigned)el << 16);
    }

    // ---- A pack + exact fp32 ||z||^2 partial ----
    frag_u a[2][2];
    float zsq = 0.f;
#pragma unroll
    for (int rt = 0; rt < 2; ++rt)
#pragma unroll
        for (int c = 0; c < 2; ++c) {
#pragma unroll
            for (int j = 0; j < 8; ++j) zsq = fmaf(av[rt][c][j], av[rt][c][j], zsq);
            a[rt][c].u.x = pk(av[rt][c][0], av[rt][c][1]);
            a[rt][c].u.y = pk(av[rt][c][2], av[rt][c][3]);
            a[rt][c].u.z = pk(av[rt][c][4], av[rt][c][5]);
            a[rt][c].u.w = pk(av[rt][c][6], av[rt][c][7]);
        }

    // ee fold-in A operand: k slots 0,1 = 1.0 (quad 0 only)
    short8 aee = {0, 0, 0, 0, 0, 0, 0, 0};
    if (quad == 0) { aee[0] = (short)0x3F80; aee[1] = (short)0x3F80; }

    float best0[4], best1[4];
#pragma unroll
    for (int r = 0; r < 4; ++r) {
        best0[r] = __uint_as_float(0x7F800000u);
        best1[r] = __uint_as_float(0x7F800000u);
    }

    __syncthreads();   // B + eepk resident; barrier-free main loop

    // ---- Main loop: 16 x 2 col-tiles ----
#pragma unroll 1
    for (int t2 = 0; t2 < 16; ++t2) {
        const int ta = 2 * t2, tb = 2 * t2 + 1;
        frag_u ba0, ba1, bb0, bb1;
        ba0.u = *(const uint4*)&sb[(ta * 2 + 0) * 512 + lane * 8];
        ba1.u = *(const uint4*)&sb[(ta * 2 + 1) * 512 + lane * 8];
        bb0.u = *(const uint4*)&sb[(tb * 2 + 0) * 512 + lane * 8];
        bb1.u = *(const uint4*)&sb[(tb * 2 + 1) * 512 + lane * 8];
        unsigned epa = eepk[ta * 16 + lx], epb = eepk[tb * 16 + lx];
        short8 beea = {0,0,0,0,0,0,0,0}, beeb = {0,0,0,0,0,0,0,0};
        if (quad == 0) {
            beea[0] = (short)(epa & 0xFFFFu); beea[1] = (short)(epa >> 16);
            beeb[0] = (short)(epb & 0xFFFFu); beeb[1] = (short)(epb >> 16);
        }

        f32x4 aa0 = {0,0,0,0}, aa1 = {0,0,0,0}, ab0 = {0,0,0,0}, ab1 = {0,0,0,0};
        aa0 = __builtin_amdgcn_mfma_f32_16x16x32_bf16(a[0][0].s, ba0.s, aa0, 0, 0, 0);
        aa1 = __builtin_amdgcn_mfma_f32_16x16x32_bf16(a[1][0].s, ba0.s, aa1, 0, 0, 0);
        ab0 = __builtin_amdgcn_mfma_f32_16x16x32_bf16(a[0][0].s, bb0.s, ab0, 0, 0, 0);
        ab1 = __builtin_amdgcn_mfma_f32_16x16x32_bf16(a[1][0].s, bb0.s, ab1, 0, 0, 0);
        aa0 = __builtin_amdgcn_mfma_f32_16x16x32_bf16(a[0][1].s, ba1.s, aa0, 0, 0, 0);
        aa1 = __builtin_amdgcn_mfma_f32_16x16x32_bf16(a[1][1].s, ba1.s, aa1, 0, 0, 0);
        ab0 = __builtin_amdgcn_mfma_f32_16x16x32_bf16(a[0][1].s, bb1.s, ab0, 0, 0, 0);
        ab1 = __builtin_amdgcn_mfma_f32_16x16x32_bf16(a[1][1].s, bb1.s, ab1, 0, 0, 0);
        aa0 = __builtin_amdgcn_mfma_f32_16x16x32_bf16(aee, beea, aa0, 0, 0, 0);
        aa1 = __builtin_amdgcn_mfma_f32_16x16x32_bf16(aee, beea, aa1, 0, 0, 0);
        ab0 = __builtin_amdgcn_mfma_f32_16x16x32_bf16(aee, beeb, ab0, 0, 0, 0);
        ab1 = __builtin_amdgcn_mfma_f32_16x16x32_bf16(aee, beeb, ab1, 0, 0, 0);

        unsigned cba = (unsigned)(ta * 16 + lx), cbb = (unsigned)(tb * 16 + lx);
#pragma unroll
        for (int r = 0; r < 4; ++r) {
            float ka0 = __uint_as_float((__float_as_uint(aa0[r]) & 0xFFFFFE00u) | cba);
            float kb0 = __uint_as_float((__float_as_uint(ab0[r]) & 0xFFFFFE00u) | cbb);
            best0[r] = fminf(fminf(best0[r], ka0), kb0);
            float ka1 = __uint_as_float((__float_as_uint(aa1[r]) & 0xFFFFFE00u) | cba);
            float kb1 = __uint_as_float((__float_as_uint(ab1[r]) & 0xFFFFFE00u) | cbb);
            best1[r] = fminf(fminf(best1[r], ka1), kb1);
        }
    }

    // ---- Cross-lane argmin (butterfly over 16 cols = low 4 lane bits) + SSE ----
    float lsse = zsq;
#pragma unroll
    for (int rt = 0; rt < 2; ++rt) {
#pragma unroll
        for (int r = 0; r < 4; ++r) {
            float v = rt == 0 ? best0[r] : best1[r];
#pragma unroll
            for (int m = 1; m < 16; m <<= 1) v = fminf(v, __shfl_xor(v, m, 64));
            if (lx == 4 * quad + r) {   // one writer per (quad, r): row = 4*quad+r
                unsigned u = __float_as_uint(v);
                int c = (int)(u & 0x1FFu);
                bks[wave * 32 + rt * 16 + 4 * quad + r] = c;
                atomicAdd(&hcnt[c], 1u);
                lsse += __uint_as_float(u & 0xFFFFFE00u);
            }
        }
    }
#pragma unroll
    for (int off = 32; off > 0; off >>= 1) lsse += __shfl_down(lsse, off, 64);
    if (lane == 0) red[wave] = lsse;

    __syncthreads();
    if (tid == 0) {
        float s = 0.f;
#pragma unroll
        for (int i = 0; i < 8; ++i) s += red[i];
        sse_arr[blockIdx.x] = s;
    }

    // ---- Epilogue: thread -> (pixel = tid&255, d-half = tid>>8) ----
    {
        int q = tid & (PPB - 1);
        int dh = tid >> 8;
        int bk = bks[q];
        const float4* Er = (const float4*)(E + bk * D + dh * 32);
        float* ob = out + 1 + (size_t)b * (D * HW) + (size_t)dh * 32 * HW + s0 + q;
#pragma unroll
        for (int v4i = 0; v4i < 8; ++v4i) {
            float4 e4 = Er[v4i];
            ob[(size_t)(4 * v4i + 0) * HW] = e4.x;
            ob[(size_t)(4 * v4i + 1) * HW] = e4.y;
            ob[(size_t)(4 * v4i + 2) * HW] = e4.z;
            ob[(size_t)(4 * v4i + 3) * HW] = e4.w;
        }
    }

    // ---- flush histogram ----
    unsigned hc = hcnt[tid];
    if (hc) atomicAdd(&counts[tid], hc);

    // ---- fused finalize: last block computes loss + perplexity ----
    __syncthreads();
    if (tid == 0) {
        __threadfence();
        unsigned t = atomicAdd(ticket, 1u);
        sflag = (t == (unsigned)(NBLK - 1)) ? 1 : 0;
    }
    __syncthreads();
    if (sflag) {
        float cf = (float)atomicAdd(&counts[tid], 0u);
        float pa = cf / (float)NPIX + 1e-10f;
        float t = pa * logf(pa);
        float s = atomicAdd(&sse_arr[tid], 0.0f);
#pragma unroll
        for (int off = 32; off > 0; off >>= 1) {
            t += __shfl_down(t, off, 64);
            s += __shfl_down(s, off, 64);
        }
        if (lane == 0) { red[wave] = t; red2[wave] = s; }
        __syncthreads();
        if (tid == 0) {
            float tot = 0.f, st = 0.f;
#pragma unroll
            for (int i = 0; i < 8; ++i) { tot += red[i]; st += red2[i]; }
            out[0] = (1.f + BETA) * st / (float)NELEM;
            out[out_size - 1] = expf(-tot);
        }
    }
}

extern "C" void kernel_launch(void* const* d_in, const int* in_sizes, int n_in,
                              void* d_out, int out_size, void* d_ws, size_t ws_size,
                              hipStream_t stream) {
    const float* z = (const float*)d_in[0];
    const float* E = (const float*)d_in[1];
    float* out = (float*)d_out;

    float* wsf = (float*)d_ws;
    unsigned int* ticket = (unsigned int*)wsf;         // [0] (+pad)
    unsigned int* counts = (unsigned int*)(wsf + 4);   // 512 uints
    float* sse_arr = wsf + 4 + K;                      // 512 floats (written unconditionally)

    hipMemsetAsync(d_ws, 0, (4 + K) * sizeof(float), stream);   // ticket + counts
    vq_one<<<NBLK, 512, 0, stream>>>(z, E, out, out_size, sse_arr, counts, ticket);
}

// Round 12
// 122.836 us; speedup vs baseline: 2.0664x; 1.0426x over previous
//
#include <hip/hip_runtime.h>
#include <math.h>

constexpr int K = 512;
constexpr int D = 64;
constexpr int HW = 64 * 64;                      // 4096
constexpr int NPIX = 131072;
constexpr long long NELEM = (long long)NPIX * D; // 8388608
constexpr float BETA = 0.25f;
constexpr int PPB = 256;                         // pixels per block
constexpr int NBLK = NPIX / PPB;                 // 512 blocks (2 per CU)

typedef __attribute__((ext_vector_type(8))) short short8;
typedef __attribute__((ext_vector_type(4))) float f32x4;

union frag_u { uint4 u; short8 s; };

__device__ inline unsigned short bf16rne(float x) {
    unsigned u = __float_as_uint(x);
    unsigned r = (u + 0x7FFFu + ((u >> 16) & 1u)) >> 16;
    return (unsigned short)r;
}

// truncated-bf16 pack: f0 -> low ushort, f1 -> high ushort (one v_perm_b32)
__device__ inline unsigned pk(float f0, float f1) {
    return __builtin_amdgcn_perm(__float_as_uint(f1), __float_as_uint(f0), 0x07060302u);
}

// Single fused kernel, 16x16x32 MFMA, liveness-shaped so everything stays in
// VGPRs under the 128-reg (512,4) budget: B built in 8 small pipelined groups,
// A packed immediately after load.
__global__ __launch_bounds__(512, 4) void vq_one(
    const float* __restrict__ z, const float* __restrict__ E,
    float* __restrict__ out, int out_size, float* __restrict__ sse_arr,
    unsigned int* __restrict__ counts, unsigned int* __restrict__ ticket) {

    __shared__ __align__(16) unsigned short sb[32768];   // 64 KB B-frags
    __shared__ unsigned int eepk[K];                     // ee hi|lo packed bf16
    __shared__ int bks[PPB];
    __shared__ unsigned int hcnt[K];
    __shared__ float red[8], red2[8];
    __shared__ int sflag;

    const int tid = threadIdx.x;
    const int wave = tid >> 6;      // 0..7
    const int lane = tid & 63;
    const int quad = lane >> 4;     // k-group
    const int lx = lane & 15;       // m for A, n for B, col for C/D

    const int p0 = blockIdx.x * PPB;
    const int b = p0 >> 12;
    const int s0 = p0 & (HW - 1);

    hcnt[tid] = 0u;

    // ---- A loads (32 scattered dwords, issued early; consumed after B build) ----
    const float* zb = z + (size_t)b * (D * HW) + s0 + wave * 32;
    float z0[16], z1[16];   // row-tile 0 / 1
#pragma unroll
    for (int c = 0; c < 2; ++c)
#pragma unroll
        for (int j = 0; j < 8; ++j) {
            size_t doff = (size_t)(c * 32 + quad * 8 + j) * HW;
            z0[c * 8 + j] = zb[doff + lx];
            z1[c * 8 + j] = zb[doff + 16 + lx];
        }

    // ---- B build: 8 pipelined groups, store-early (low liveness) ----
    // element k = g*8+j ; frag slot: (tile*2 + (g>>2))*512 + ((g&3)*16 + col)*8
    {
        const int n = tid;
        const float4* er = (const float4*)(E + n * D);
        const int tile = n >> 4, col = n & 15;
        float acc = 0.f;
        float4 c0 = er[0], c1 = er[1];
#pragma unroll
        for (int g = 0; g < 8; ++g) {
            float4 n0, n1;
            if (g < 7) { n0 = er[2 * g + 2]; n1 = er[2 * g + 3]; }
            acc = fmaf(c0.x, c0.x, acc); acc = fmaf(c0.y, c0.y, acc);
            acc = fmaf(c0.z, c0.z, acc); acc = fmaf(c0.w, c0.w, acc);
            acc = fmaf(c1.x, c1.x, acc); acc = fmaf(c1.y, c1.y, acc);
            acc = fmaf(c1.z, c1.z, acc); acc = fmaf(c1.w, c1.w, acc);
            uint4 w;
            w.x = pk(-2.f * c0.x, -2.f * c0.y);
            w.y = pk(-2.f * c0.z, -2.f * c0.w);
            w.z = pk(-2.f * c1.x, -2.f * c1.y);
            w.w = pk(-2.f * c1.z, -2.f * c1.w);
            *(uint4*)&sb[(tile * 2 + (g >> 2)) * 512 + ((g & 3) * 16 + col) * 8] = w;
            c0 = n0; c1 = n1;
        }
        unsigned short eh = bf16rne(acc);
        unsigned short el = bf16rne(acc - __uint_as_float((unsigned)eh << 16));
        eepk[n] = (unsigned)eh | ((unsigned)el << 16);
    }

    // ---- A pack + exact fp32 ||z||^2 (frees the 32 raw floats) ----
    frag_u a[2][2];
    float zsq = 0.f;
#pragma unroll
    for (int c = 0; c < 2; ++c) {
#pragma unroll
        for (int j = 0; j < 8; ++j) {
            zsq = fmaf(z0[c * 8 + j], z0[c * 8 + j], zsq);
            zsq = fmaf(z1[c * 8 + j], z1[c * 8 + j], zsq);
        }
        a[0][c].u.x = pk(z0[c * 8 + 0], z0[c * 8 + 1]);
        a[0][c].u.y = pk(z0[c * 8 + 2], z0[c * 8 + 3]);
        a[0][c].u.z = pk(z0[c * 8 + 4], z0[c * 8 + 5]);
        a[0][c].u.w = pk(z0[c * 8 + 6], z0[c * 8 + 7]);
        a[1][c].u.x = pk(z1[c * 8 + 0], z1[c * 8 + 1]);
        a[1][c].u.y = pk(z1[c * 8 + 2], z1[c * 8 + 3]);
        a[1][c].u.z = pk(z1[c * 8 + 4], z1[c * 8 + 5]);
        a[1][c].u.w = pk(z1[c * 8 + 6], z1[c * 8 + 7]);
    }

    // ee fold-in A operand: k slots 0,1 = 1.0 (quad 0 only) -> one uint
    frag_u aee;
    aee.u.x = (quad == 0) ? 0x3F803F80u : 0u;
    aee.u.y = 0u; aee.u.z = 0u; aee.u.w = 0u;

    float best0[4], best1[4];
#pragma unroll
    for (int r = 0; r < 4; ++r) {
        best0[r] = __uint_as_float(0x7F800000u);
        best1[r] = __uint_as_float(0x7F800000u);
    }

    __syncthreads();   // B + eepk resident; barrier-free main loop

    // ---- Main loop: 16 x 2 col-tiles ----
#pragma unroll 1
    for (int t2 = 0; t2 < 16; ++t2) {
        const int ta = 2 * t2, tb = 2 * t2 + 1;
        frag_u ba0, ba1, bb0, bb1;
        ba0.u = *(const uint4*)&sb[(ta * 2 + 0) * 512 + lane * 8];
        ba1.u = *(const uint4*)&sb[(ta * 2 + 1) * 512 + lane * 8];
        bb0.u = *(const uint4*)&sb[(tb * 2 + 0) * 512 + lane * 8];
        bb1.u = *(const uint4*)&sb[(tb * 2 + 1) * 512 + lane * 8];
        frag_u beea, beeb;
        beea.u.x = (quad == 0) ? eepk[ta * 16 + lx] : 0u;
        beea.u.y = 0u; beea.u.z = 0u; beea.u.w = 0u;
        beeb.u.x = (quad == 0) ? eepk[tb * 16 + lx] : 0u;
        beeb.u.y = 0u; beeb.u.z = 0u; beeb.u.w = 0u;

        f32x4 aa0 = {0,0,0,0}, aa1 = {0,0,0,0}, ab0 = {0,0,0,0}, ab1 = {0,0,0,0};
        aa0 = __builtin_amdgcn_mfma_f32_16x16x32_bf16(a[0][0].s, ba0.s, aa0, 0, 0, 0);
        aa1 = __builtin_amdgcn_mfma_f32_16x16x32_bf16(a[1][0].s, ba0.s, aa1, 0, 0, 0);
        ab0 = __builtin_amdgcn_mfma_f32_16x16x32_bf16(a[0][0].s, bb0.s, ab0, 0, 0, 0);
        ab1 = __builtin_amdgcn_mfma_f32_16x16x32_bf16(a[1][0].s, bb0.s, ab1, 0, 0, 0);
        aa0 = __builtin_amdgcn_mfma_f32_16x16x32_bf16(a[0][1].s, ba1.s, aa0, 0, 0, 0);
        aa1 = __builtin_amdgcn_mfma_f32_16x16x32_bf16(a[1][1].s, ba1.s, aa1, 0, 0, 0);
        ab0 = __builtin_amdgcn_mfma_f32_16x16x32_bf16(a[0][1].s, bb1.s, ab0, 0, 0, 0);
        ab1 = __builtin_amdgcn_mfma_f32_16x16x32_bf16(a[1][1].s, bb1.s, ab1, 0, 0, 0);
        aa0 = __builtin_amdgcn_mfma_f32_16x16x32_bf16(aee.s, beea.s, aa0, 0, 0, 0);
        aa1 = __builtin_amdgcn_mfma_f32_16x16x32_bf16(aee.s, beea.s, aa1, 0, 0, 0);
        ab0 = __builtin_amdgcn_mfma_f32_16x16x32_bf16(aee.s, beeb.s, ab0, 0, 0, 0);
        ab1 = __builtin_amdgcn_mfma_f32_16x16x32_bf16(aee.s, beeb.s, ab1, 0, 0, 0);

        unsigned cba = (unsigned)(ta * 16 + lx), cbb = (unsigned)(tb * 16 + lx);
#pragma unroll
        for (int r = 0; r < 4; ++r) {
            float ka0 = __uint_as_float((__float_as_uint(aa0[r]) & 0xFFFFFE00u) | cba);
            float kb0 = __uint_as_float((__float_as_uint(ab0[r]) & 0xFFFFFE00u) | cbb);
            best0[r] = fminf(fminf(best0[r], ka0), kb0);
            float ka1 = __uint_as_float((__float_as_uint(aa1[r]) & 0xFFFFFE00u) | cba);
            float kb1 = __uint_as_float((__float_as_uint(ab1[r]) & 0xFFFFFE00u) | cbb);
            best1[r] = fminf(fminf(best1[r], ka1), kb1);
        }
    }

    // ---- Cross-lane argmin (butterfly over low 4 lane bits) + SSE ----
    float lsse = zsq;
#pragma unroll
    for (int rt = 0; rt < 2; ++rt) {
#pragma unroll
        for (int r = 0; r < 4; ++r) {
            float v = rt == 0 ? best0[r] : best1[r];
#pragma unroll
            for (int m = 1; m < 16; m <<= 1) v = fminf(v, __shfl_xor(v, m, 64));
            if (lx == 4 * quad + r) {   // one writer per (quad,r): row = 4*quad+r
                unsigned u = __float_as_uint(v);
                int c = (int)(u & 0x1FFu);
                bks[wave * 32 + rt * 16 + 4 * quad + r] = c;
                atomicAdd(&hcnt[c], 1u);
                lsse += __uint_as_float(u & 0xFFFFFE00u);
            }
        }
    }
#pragma unroll
    for (int off = 32; off > 0; off >>= 1) lsse += __shfl_down(lsse, off, 64);
    if (lane == 0) red[wave] = lsse;

    __syncthreads();
    if (tid == 0) {
        float s = 0.f;
#pragma unroll
        for (int i = 0; i < 8; ++i) s += red[i];
        sse_arr[blockIdx.x] = s;
    }

    // ---- Epilogue: thread -> (pixel = tid&255, d-half = tid>>8) ----
    {
        int q = tid & (PPB - 1);
        int dh = tid >> 8;
        int bk = bks[q];
        const float4* Er = (const float4*)(E + bk * D + dh * 32);
        float* ob = out + 1 + (size_t)b * (D * HW) + (size_t)dh * 32 * HW + s0 + q;
#pragma unroll
        for (int v4i = 0; v4i < 8; ++v4i) {
            float4 e4 = Er[v4i];
            ob[(size_t)(4 * v4i + 0) * HW] = e4.x;
            ob[(size_t)(4 * v4i + 1) * HW] = e4.y;
            ob[(size_t)(4 * v4i + 2) * HW] = e4.z;
            ob[(size_t)(4 * v4i + 3) * HW] = e4.w;
        }
    }

    // ---- flush histogram ----
    unsigned hc = hcnt[tid];
    if (hc) atomicAdd(&counts[tid], hc);

    // ---- fused finalize: last block computes loss + perplexity ----
    __syncthreads();
    if (tid == 0) {
        __threadfence();
        unsigned t = atomicAdd(ticket, 1u);
        sflag = (t == (unsigned)(NBLK - 1)) ? 1 : 0;
    }
    __syncthreads();
    if (sflag) {
        float cf = (float)atomicAdd(&counts[tid], 0u);
        float pa = cf / (float)NPIX + 1e-10f;
        float t = pa * logf(pa);
        float s = atomicAdd(&sse_arr[tid], 0.0f);
#pragma unroll
        for (int off = 32; off > 0; off >>= 1) {
            t += __shfl_down(t, off, 64);
            s += __shfl_down(s, off, 64);
        }
        if (lane == 0) { red[wave] = t; red2[wave] = s; }
        __syncthreads();
        if (tid == 0) {
            float tot = 0.f, st = 0.f;
#pragma unroll
            for (int i = 0; i < 8; ++i) { tot += red[i]; st += red2[i]; }
            out[0] = (1.f + BETA) * st / (float)NELEM;
            out[out_size - 1] = expf(-tot);
        }
    }
}

extern "C" void kernel_launch(void* const* d_in, const int* in_sizes, int n_in,
                              void* d_out, int out_size, void* d_ws, size_t ws_size,
                              hipStream_t stream) {
    const float* z = (const float*)d_in[0];
    const float* E = (const float*)d_in[1];
    float* out = (float*)d_out;

    float* wsf = (float*)d_ws;
    unsigned int* ticket = (unsigned int*)wsf;         // [0] (+pad)
    unsigned int* counts = (unsigned int*)(wsf + 4);   // 512 uints
    float* sse_arr = wsf + 4 + K;                      // 512 floats (written unconditionally)

    hipMemsetAsync(d_ws, 0, (4 + K) * sizeof(float), stream);   // ticket + counts
    vq_one<<<NBLK, 512, 0, stream>>>(z, E, out, out_size, sse_arr, counts, ticket);
}